// Round 9
// baseline (27.974 us; speedup 1.0000x reference)
//
#include <hip/hip_runtime.h>
#include <math.h>

#define HALF 5
#define BLOCK 1024
#define EPT 4             // outputs per thread -> lane-consecutive float4 I/O
#define TILE (BLOCK*EPT)  // 4096 outputs per block

typedef float floatx4 __attribute__((ext_vector_type(4)));

__global__ __launch_bounds__(BLOCK) void dilation1d_kernel(
    const float* __restrict__ in, const float* __restrict__ scale_p,
    float* __restrict__ out, int N)
{
    const float inv4s = 1.0f / (4.0f * scale_p[0]);
    // h[d] = -(d^2)/(4*scale); symmetric; h[0] = -0.0 (exact identity add)
    float h[HALF + 1];
    #pragma unroll
    for (int d = 0; d <= HALF; ++d) h[d] = -(float)(d * d) * inv4s;

    const int t = threadIdx.x;
    const int base  = blockIdx.x * TILE + t * EPT; // first output index
    const int lbase = base - 8;                    // 16B-aligned first loaded idx

    // r[j] = in[base-8+j], j=0..19 ; windows need j = u+3 .. u+13, u<4
    // For fixed v, lanes read lbase + v*16B with lbase lane-consecutive:
    // each load instruction covers 1KB contiguous per wave -> fully coalesced.
    float r[20];
    const bool interior = (blockIdx.x != 0) && (blockIdx.x != gridDim.x - 1);
    if (interior) {
        const floatx4* p = (const floatx4*)(in + lbase);
        #pragma unroll
        for (int v = 0; v < 5; ++v) {
            floatx4 f = p[v];
            r[v*4+0] = f.x; r[v*4+1] = f.y; r[v*4+2] = f.z; r[v*4+3] = f.w;
        }
    } else {
        #pragma unroll
        for (int j = 0; j < 20; ++j) {
            int idx = lbase + j;
            r[j] = ((unsigned)idx < (unsigned)N) ? in[idx] : -INFINITY;
        }
    }

    // out[base+u] = max_d ( max(x[i-d], x[i+d]) + h[d] ), center tap free.
    // Bit-exact vs reference: RN monotone => max(a,b)+h == max(a+h,b+h).
    float o[EPT];
    #pragma unroll
    for (int u = 0; u < EPT; ++u) {
        float m = r[u + 8];
        #pragma unroll
        for (int d = 1; d <= HALF; ++d)
            m = fmaxf(m, fmaxf(r[u + 8 - d], r[u + 8 + d]) + h[d]);
        o[u] = m;
    }

    if (interior) {
        floatx4 w = {o[0], o[1], o[2], o[3]};
        *(floatx4*)(out + base) = w;   // lane-consecutive 16B -> perfect coalescing
    } else {
        #pragma unroll
        for (int u = 0; u < EPT; ++u)
            if (base + u < N) out[base + u] = o[u];
    }
}

extern "C" void kernel_launch(void* const* d_in, const int* in_sizes, int n_in,
                              void* d_out, int out_size, void* d_ws, size_t ws_size,
                              hipStream_t stream) {
    const float* in      = (const float*)d_in[0];
    const float* scale_p = (const float*)d_in[1];
    float* out           = (float*)d_out;
    const int N = in_sizes[0];
    const int grid = (N + TILE - 1) / TILE;
    hipLaunchKernelGGL(dilation1d_kernel, dim3(grid), dim3(BLOCK), 0, stream,
                       in, scale_p, out, N);
}

// Round 10
// 25.984 us; speedup vs baseline: 1.0766x; 1.0766x over previous
//
#include <hip/hip_runtime.h>
#include <math.h>

#define HALF 5
#define BLOCK 256
#define EPT 4             // outputs per thread -> lane-consecutive float4 I/O
#define TILE (BLOCK*EPT)  // 1024 outputs per block

typedef float floatx4 __attribute__((ext_vector_type(4)));

__global__ __launch_bounds__(BLOCK) void dilation1d_kernel(
    const float* __restrict__ in, const float* __restrict__ scale_p,
    float* __restrict__ out, int N)
{
    const float inv4s = 1.0f / (4.0f * scale_p[0]);
    // h[d] = -(d^2)/(4*scale); symmetric; h[0] = -0.0 (exact identity add)
    float h[HALF + 1];
    #pragma unroll
    for (int d = 0; d <= HALF; ++d) h[d] = -(float)(d * d) * inv4s;

    const int t = threadIdx.x;
    const int base  = blockIdx.x * TILE + t * EPT; // first output index
    const int lbase = base - 8;                    // 16B-aligned first loaded idx

    // r[j] = in[base-8+j], j=0..19 ; windows need j = u+3 .. u+13, u<4
    // For fixed v, lanes read lbase + v*16B with lbase lane-consecutive:
    // each load instruction covers 1KB contiguous per wave -> fully coalesced.
    float r[20];
    const bool interior = (blockIdx.x != 0) && (blockIdx.x != gridDim.x - 1);
    if (interior) {
        const floatx4* p = (const floatx4*)(in + lbase);
        #pragma unroll
        for (int v = 0; v < 5; ++v) {
            floatx4 f = p[v];
            r[v*4+0] = f.x; r[v*4+1] = f.y; r[v*4+2] = f.z; r[v*4+3] = f.w;
        }
    } else {
        #pragma unroll
        for (int j = 0; j < 20; ++j) {
            int idx = lbase + j;
            r[j] = ((unsigned)idx < (unsigned)N) ? in[idx] : -INFINITY;
        }
    }

    // out[base+u] = max_d ( max(x[i-d], x[i+d]) + h[d] ), center tap free.
    // Bit-exact vs reference: RN monotone => max(a,b)+h == max(a+h,b+h).
    float o[EPT];
    #pragma unroll
    for (int u = 0; u < EPT; ++u) {
        float m = r[u + 8];
        #pragma unroll
        for (int d = 1; d <= HALF; ++d)
            m = fmaxf(m, fmaxf(r[u + 8 - d], r[u + 8 + d]) + h[d]);
        o[u] = m;
    }

    if (interior) {
        // Lane-consecutive 16B stores: each wave inst = 8 full 128B lines.
        // NT here cannot cause partial-sector amplification (round-4's bug);
        // it only skips L2/L3 allocation for the never-re-read output stream.
        floatx4 w = {o[0], o[1], o[2], o[3]};
        __builtin_nontemporal_store(w, (floatx4*)(out + base));
    } else {
        #pragma unroll
        for (int u = 0; u < EPT; ++u)
            if (base + u < N) out[base + u] = o[u];
    }
}

extern "C" void kernel_launch(void* const* d_in, const int* in_sizes, int n_in,
                              void* d_out, int out_size, void* d_ws, size_t ws_size,
                              hipStream_t stream) {
    const float* in      = (const float*)d_in[0];
    const float* scale_p = (const float*)d_in[1];
    float* out           = (float*)d_out;
    const int N = in_sizes[0];
    const int grid = (N + TILE - 1) / TILE;
    hipLaunchKernelGGL(dilation1d_kernel, dim3(grid), dim3(BLOCK), 0, stream,
                       in, scale_p, out, N);
}